// Round 24
// baseline (392.093 us; speedup 1.0000x reference)
//
#include <hip/hip_runtime.h>
#include <hip/hip_fp8.h>
#include <math.h>

typedef unsigned short u16;
typedef unsigned char u8;
typedef short s16x8 __attribute__((ext_vector_type(8)));
typedef short s16x4 __attribute__((ext_vector_type(4)));
typedef unsigned int u32x4 __attribute__((ext_vector_type(4)));
typedef unsigned int u32x2 __attribute__((ext_vector_type(2)));
typedef float f32x4 __attribute__((ext_vector_type(4)));
typedef unsigned short u16x2 __attribute__((ext_vector_type(2)));

__device__ __forceinline__ float bf2f(u16 u) {
  unsigned x = ((unsigned)u) << 16;
  return __builtin_bit_cast(float, x);
}
__device__ __forceinline__ u16 f2bf(float f) {
  unsigned x = __builtin_bit_cast(unsigned, f);
  unsigned r = (x + 0x7FFFu + ((x >> 16) & 1u)) >> 16;
  return (u16)r;
}
__device__ __forceinline__ u8 f2e4(float f) {
  __hip_fp8_e4m3 q(f);
  return (u8)q.__x;
}
__device__ __forceinline__ float e42f(unsigned b) {
  __hip_fp8_e4m3 h;
  h.__x = (unsigned char)b;
  return (float)h;
}
__device__ __forceinline__ unsigned cvt2e4(float a, float b) {
#if __has_builtin(__builtin_amdgcn_cvt_pk_fp8_f32)
  return (unsigned)__builtin_amdgcn_cvt_pk_fp8_f32(a, b, 0, false) & 0xFFFFu;
#else
  return (unsigned)f2e4(a) | ((unsigned)f2e4(b) << 8);
#endif
}

// ---- fp8 MFMA: builtin operand type is 'long' (i64) on gfx950 ----
__device__ __forceinline__ f32x4 mfma8(long a, long b, f32x4 c) {
  return __builtin_amdgcn_mfma_f32_16x16x32_fp8_fp8(a, b, c, 0, 0, 0);
}

// ---- in-block gather+LayerNorm (fp8 t): 32 rows -> fp8 octet layout in Alds ----
// 256 thr: row = tid>>3, seg = tid&7 (48 values each = 3x16B loads).
__device__ __forceinline__ void stage_ln(
    const u8* __restrict__ t, const int* __restrict__ rm, int m_base,
    const float* __restrict__ nw, const float* __restrict__ nb, u8* Alds,
    int tid) {
  int row = tid >> 3, seg = tid & 7;
  const u8* src = t + (size_t)rm[m_base + row] * 384 + seg * 48;
  u32x4 raw[3];
#pragma unroll
  for (int o = 0; o < 3; ++o) raw[o] = *(const u32x4*)(src + o * 16);
  float s = 0.f, q = 0.f;
#pragma unroll
  for (int o = 0; o < 3; ++o)
#pragma unroll
    for (int w = 0; w < 4; ++w) {
      unsigned d = raw[o][w];
      float v0 = e42f(d & 0xFFu);
      float v1 = e42f((d >> 8) & 0xFFu);
      float v2 = e42f((d >> 16) & 0xFFu);
      float v3 = e42f(d >> 24);
      s += (v0 + v1) + (v2 + v3);
      q += (v0 * v0 + v1 * v1) + (v2 * v2 + v3 * v3);
    }
#pragma unroll
  for (int off = 1; off <= 4; off <<= 1) {
    s += __shfl_xor(s, off);
    q += __shfl_xor(q, off);
  }
  float mu = s * (1.f / 384.f);
  float var = q * (1.f / 384.f) - mu * mu;
  float rs = rsqrtf(var + 1e-6f);
#pragma unroll
  for (int o2 = 0; o2 < 6; ++o2) {
    unsigned dA = raw[o2 >> 1][(o2 & 1) * 2];
    unsigned dB = raw[o2 >> 1][(o2 & 1) * 2 + 1];
    int k0 = seg * 48 + o2 * 8;
    float4 w0 = *(const float4*)(nw + k0);
    float4 w1 = *(const float4*)(nw + k0 + 4);
    float4 c0 = *(const float4*)(nb + k0);
    float4 c1 = *(const float4*)(nb + k0 + 4);
    float g0 = (e42f(dA & 0xFFu) - mu) * rs * w0.x + c0.x;
    float g1 = (e42f((dA >> 8) & 0xFFu) - mu) * rs * w0.y + c0.y;
    float g2 = (e42f((dA >> 16) & 0xFFu) - mu) * rs * w0.z + c0.z;
    float g3 = (e42f(dA >> 24) - mu) * rs * w0.w + c0.w;
    float g4 = (e42f(dB & 0xFFu) - mu) * rs * w1.x + c1.x;
    float g5 = (e42f((dB >> 8) & 0xFFu) - mu) * rs * w1.y + c1.y;
    float g6 = (e42f((dB >> 16) & 0xFFu) - mu) * rs * w1.z + c1.z;
    float g7 = (e42f(dB >> 24) - mu) * rs * w1.w + c1.w;
    u32x2 pk;
    pk[0] = cvt2e4(g0, g1) | (cvt2e4(g2, g3) << 16);
    pk[1] = cvt2e4(g4, g5) | (cvt2e4(g6, g7) << 16);
    *(u32x2*)&Alds[((seg * 6 + o2) * 32 + row) * 8] = pk;
  }
}

// ---------------- PREP (merged): dwconv (blocks 0..6143) || pack (6144..7167) ----
__global__ __launch_bounds__(256) void prep_kernel(
    const float* __restrict__ x, const float* __restrict__ dww,
    const float* __restrict__ dwb, u8* __restrict__ t,
    const float* __restrict__ w1, const float* __restrict__ w2,
    const float* __restrict__ fpw, const int* __restrict__ idx1,
    const int* __restrict__ idx2, u8* __restrict__ w1p8, u8* __restrict__ w2p8,
    u8* __restrict__ fpw8, int* __restrict__ rm1, int* __restrict__ rm2) {
  __shared__ __align__(16) u16 plane[8 * 34 * 40];  // 21760 B
  int tid = threadIdx.x;
  int bid = blockIdx.x;
  if (bid >= 6144) {
    const int T1 = 589824, T2 = T1 + 589824, T3 = T2 + 147456,
              T4 = T3 + 50176, T5 = T4 + 50176;
    for (int i = (bid - 6144) * 256 + tid; i < T5; i += 1024 * 256) {
      if (i < T1) {
        int k = i / 1536, n = i - k * 1536;
        w1p8[((size_t)(k >> 3) * 1536 + n) * 8 + (k & 7)] = f2e4(w1[i] * 64.f);
      } else if (i < T2) {
        int v = i - T1;
        int k = v / 384, n = v - k * 384;
        w2p8[((size_t)(k >> 3) * 384 + n) * 8 + (k & 7)] = f2e4(w2[v] * 64.f);
      } else if (i < T3) {
        int v = i - T2;
        int k = v / 384, n = v - k * 384;
        fpw8[((size_t)(k >> 3) * 384 + n) * 8 + (k & 7)] = f2e4(fpw[v] * 64.f);
      } else if (i < T4) {
        int g = i - T3;
        rm1[g] = (g / 392) * 784 + idx1[g];
      } else {
        int g = i - T4;
        rm2[g] = (g / 392) * 784 + idx2[g];
      }
    }
    return;
  }
  // ---- dwconv path ----
  int b = bid / 48, c0 = (bid - b * 48) * 8;
  int ch = tid & 7, row = tid >> 3;
  int c = c0 + ch;

  float wg[49];
#pragma unroll
  for (int k2 = 0; k2 < 49; ++k2) wg[k2] = dww[c * 49 + k2];
  float bias = dwb[c];

  for (int q = tid; q < 1360; q += 256) {
    s16x8 z = {0, 0, 0, 0, 0, 0, 0, 0};
    *(s16x8*)(&plane[q * 8]) = z;
  }
  __syncthreads();
  for (int q = tid; q < 1568; q += 256) {
    int cc = q / 196, seg = q - cc * 196;
    int i = seg / 7, j4 = seg - i * 7;
    const float4 v = *(const float4*)(x + ((size_t)(b * 384 + c0 + cc)) * 784 +
                                      i * 28 + j4 * 4);
    s16x4 p;
    p[0] = (short)f2bf(v.x);
    p[1] = (short)f2bf(v.y);
    p[2] = (short)f2bf(v.z);
    p[3] = (short)f2bf(v.w);
    *(s16x4*)(&plane[cc * 1360 + (3 + i) * 40 + 4 + j4 * 4]) = p;
  }
  __syncthreads();

  if (row < 28) {
    size_t obase = ((size_t)(b * 784 + row * 28)) * 384 + c;
#pragma unroll
    for (int ck = 0; ck < 4; ++ck) {
      float acc[8];
#pragma unroll
      for (int o = 0; o < 8; ++o) acc[o] = bias;
#pragma unroll
      for (int di = 0; di < 7; ++di) {
        const u16* base2 = &plane[ch * 1360 + (row + di) * 40 + ck * 8];
        u32x4 ga = *(const u32x4*)(base2);
        u32x4 gb = *(const u32x4*)(base2 + 8);
        unsigned dw[8] = {ga[0], ga[1], ga[2], ga[3],
                          gb[0], gb[1], gb[2], gb[3]};
        float v[16];
#pragma unroll
        for (int tt = 0; tt < 16; ++tt) {
          unsigned d = dw[tt >> 1];
          v[tt] = (tt & 1) ? __builtin_bit_cast(float, d & 0xFFFF0000u)
                           : __builtin_bit_cast(float, d << 16);
        }
#pragma unroll
        for (int o = 0; o < 8; ++o)
#pragma unroll
          for (int dj = 0; dj < 7; ++dj)
            acc[o] += v[o + dj + 1] * wg[di * 7 + dj];
      }
      int lim = (ck == 3) ? 4 : 8;
#pragma unroll
      for (int o = 0; o < 8; ++o)
        if (o < lim) t[obase + (size_t)(ck * 8 + o) * 384] = f2e4(acc[o]);
    }
  }
}

// ---------------- MLP (merged): fused MLP (blocks 0..1567) || gemm5 (1568..3135)
__global__ __launch_bounds__(256, 4) void mlp_kernel(
    const u8* __restrict__ t, const int* __restrict__ rm1,
    const int* __restrict__ rm2, const float* __restrict__ nw,
    const float* __restrict__ nb, const float* __restrict__ fnw,
    const float* __restrict__ fnb, const u8* __restrict__ w1p8,
    const u8* __restrict__ w2p8, const u8* __restrict__ fpw8,
    const float* __restrict__ b1, const float* __restrict__ b2,
    const float* __restrict__ gamma, const float* __restrict__ fpb,
    const float* __restrict__ fpg, u16* __restrict__ U) {
  __shared__ __align__(16) u8 Alds[48 * 32 * 8];     // 12288 B
  __shared__ __align__(16) u8 Plds[2][24 * 32 * 8];  // 2 x 6144 B
  int tid = threadIdx.x;
  int wid = tid >> 6, lane = tid & 63;
  int kgl = lane >> 4, rl = lane & 15;
  int cl = lane & 15, rg = (lane >> 4) * 4;
  int bid = blockIdx.x;
  const f32x4 vzero = {0.f, 0.f, 0.f, 0.f};

  if (bid >= 1568) {
    // ---- gemm5 path: U[rm2] = (LN(t[rm2]) @ fp_w + fp_b) * fp_gamma ----
    int m_base = (bid - 1568) * 32;
    stage_ln(t, rm2, m_base, fnw, fnb, Alds, tid);
    f32x4 acc[2][6];
#pragma unroll
    for (int i = 0; i < 2; ++i)
#pragma unroll
      for (int j = 0; j < 6; ++j) acc[i][j] = vzero;
    __syncthreads();
#pragma unroll
    for (int ks = 0; ks < 12; ++ks) {
      long af[2], bw[6];
#pragma unroll
      for (int i = 0; i < 2; ++i)
        af[i] = *(const long*)&Alds[((ks * 4 + kgl) * 32 + i * 16 + rl) * 8];
#pragma unroll
      for (int j = 0; j < 6; ++j) {
        int col = wid * 96 + j * 16 + rl;
        bw[j] = *(const long*)(fpw8 + ((size_t)(ks * 4 + kgl) * 384 + col) * 8);
      }
      __builtin_amdgcn_s_setprio(1);
#pragma unroll
      for (int i = 0; i < 2; ++i)
#pragma unroll
        for (int j = 0; j < 6; ++j)
          acc[i][j] = mfma8(af[i], bw[j], acc[i][j]);
      __builtin_amdgcn_s_setprio(0);
    }
#pragma unroll
    for (int i = 0; i < 2; ++i) {
#pragma unroll
      for (int reg = 0; reg < 4; ++reg) {
        int m = m_base + i * 16 + rg + reg;
        size_t rowoff = (size_t)rm2[m] * 384;
#pragma unroll
        for (int j = 0; j < 6; ++j) {
          int col = wid * 96 + j * 16 + cl;
          float v = (acc[i][j][reg] * 0.015625f + fpb[col]) * fpg[col];
          U[rowoff + col] = f2bf(v);
        }
      }
    }
    return;
  }

  // ---- fused MLP path: U[rm1] = (gelu(LN(t[rm1])@W1+b1)@W2 + b2)*gamma ----
  int m_base = bid * 32;
  stage_ln(t, rm1, m_base, nw, nb, Alds, tid);

  f32x4 accB[2][6];
#pragma unroll
  for (int i = 0; i < 2; ++i)
#pragma unroll
    for (int j = 0; j < 6; ++j) accB[i][j] = vzero;

  __syncthreads();

#pragma unroll 1
  for (int c = 0; c < 8; ++c) {
    u8* Pl = Plds[c & 1];
    f32x4 accA[2][3];
#pragma unroll
    for (int i = 0; i < 2; ++i)
#pragma unroll
      for (int j = 0; j < 3; ++j) accA[i][j] = vzero;
#pragma unroll
    for (int ks = 0; ks < 12; ++ks) {
      long af[2], bw[3];
#pragma unroll
      for (int i = 0; i < 2; ++i)
        af[i] = *(const long*)&Alds[((ks * 4 + kgl) * 32 + i * 16 + rl) * 8];
#pragma unroll
      for (int j = 0; j < 3; ++j) {
        int col = c * 192 + wid * 48 + j * 16 + rl;
        bw[j] = *(const long*)(w1p8 + ((size_t)(ks * 4 + kgl) * 1536 + col) * 8);
      }
      __builtin_amdgcn_s_setprio(1);
#pragma unroll
      for (int i = 0; i < 2; ++i)
#pragma unroll
        for (int j = 0; j < 3; ++j)
          accA[i][j] = mfma8(af[i], bw[j], accA[i][j]);
      __builtin_amdgcn_s_setprio(0);
    }
    float b1v[3];
#pragma unroll
    for (int j = 0; j < 3; ++j) b1v[j] = b1[c * 192 + wid * 48 + j * 16 + cl];
#pragma unroll
    for (int i = 0; i < 2; ++i)
#pragma unroll
      for (int j = 0; j < 3; ++j) {
        int col = wid * 48 + j * 16 + cl;
        float g2[4];
#pragma unroll
        for (int reg = 0; reg < 4; ++reg) {
          float v = accA[i][j][reg] * 0.015625f + b1v[j];
          g2[reg] = v * fminf(fmaxf(0.4255f * v + 0.5f, 0.f), 1.f);
        }
        unsigned p01 = cvt2e4(g2[0], g2[1]);
        unsigned p23 = cvt2e4(g2[2], g2[3]);
        int base = ((col >> 3) * 32 + i * 16 + rg) * 8 + (col & 7);
        Pl[base] = (u8)p01;
        Pl[base + 8] = (u8)(p01 >> 8);
        Pl[base + 16] = (u8)p23;
        Pl[base + 24] = (u8)(p23 >> 8);
      }
    __syncthreads();
#pragma unroll
    for (int ks = 0; ks < 6; ++ks) {
      long ap[2], bw2[6];
#pragma unroll
      for (int i = 0; i < 2; ++i)
        ap[i] = *(const long*)&Pl[((ks * 4 + kgl) * 32 + i * 16 + rl) * 8];
#pragma unroll
      for (int j = 0; j < 6; ++j) {
        int col = wid * 96 + j * 16 + rl;
        int ko2 = c * 24 + ks * 4 + kgl;
        bw2[j] = *(const long*)(w2p8 + ((size_t)ko2 * 384 + col) * 8);
      }
      __builtin_amdgcn_s_setprio(1);
#pragma unroll
      for (int i = 0; i < 2; ++i)
#pragma unroll
        for (int j = 0; j < 6; ++j)
          accB[i][j] = mfma8(ap[i], bw2[j], accB[i][j]);
      __builtin_amdgcn_s_setprio(0);
    }
  }

#pragma unroll
  for (int i = 0; i < 2; ++i) {
#pragma unroll
    for (int reg = 0; reg < 4; ++reg) {
      int m = m_base + i * 16 + rg + reg;
      size_t rowoff = (size_t)rm1[m] * 384;
#pragma unroll
      for (int j = 0; j < 6; ++j) {
        int col = wid * 96 + j * 16 + cl;
        float v = (accB[i][j][reg] * 0.015625f + b2[col]) * gamma[col];
        U[rowoff + col] = f2bf(v);
      }
    }
  }
}

// ---------------- K6: un-transpose (B,N,C)->(B,C,N) + residual add ----------------
__global__ __launch_bounds__(256) void unscatter_add_kernel(
    const u16* __restrict__ U, const float* __restrict__ x,
    float* __restrict__ out) {
  __shared__ float tile[32][129];
  int b = blockIdx.y;
  int ct = blockIdx.x % 12, nt = blockIdx.x / 12;
  int c0 = ct * 32, n0 = nt * 128;
  int tid = threadIdx.x;
#pragma unroll
  for (int it = 0; it < 4; ++it) {
    int q = tid + it * 256;
    int nl = q >> 3, cg = (q & 7) * 4;
    int n = n0 + nl;
    if (n < 784) {
      s16x4 v = *(const s16x4*)(U + ((size_t)(b * 784 + n)) * 384 + c0 + cg);
      tile[cg + 0][nl] = bf2f((u16)v[0]);
      tile[cg + 1][nl] = bf2f((u16)v[1]);
      tile[cg + 2][nl] = bf2f((u16)v[2]);
      tile[cg + 3][nl] = bf2f((u16)v[3]);
    }
  }
  __syncthreads();
#pragma unroll
  for (int it = 0; it < 4; ++it) {
    int q = tid + it * 256;
    int c = q >> 5, nf = (q & 31) * 4;
    int n = n0 + nf;
    if (n + 3 < 784) {
      size_t o = ((size_t)(b * 384 + c0 + c)) * 784 + n;
      float4 xv = *(const float4*)(x + o);
      float4 r;
      r.x = xv.x + tile[c][nf + 0];
      r.y = xv.y + tile[c][nf + 1];
      r.z = xv.z + tile[c][nf + 2];
      r.w = xv.w + tile[c][nf + 3];
      *(float4*)(out + o) = r;
    }
  }
}

extern "C" void kernel_launch(void* const* d_in, const int* in_sizes, int n_in,
                              void* d_out, int out_size, void* d_ws,
                              size_t ws_size, hipStream_t stream) {
  const float* x = (const float*)d_in[0];
  const int* idx1 = (const int*)d_in[1];
  const int* idx2 = (const int*)d_in[2];
  const float* dww = (const float*)d_in[3];
  const float* dwb = (const float*)d_in[4];
  const float* nw = (const float*)d_in[5];
  const float* nb = (const float*)d_in[6];
  const float* w1 = (const float*)d_in[7];
  const float* b1 = (const float*)d_in[8];
  const float* w2 = (const float*)d_in[9];
  const float* b2 = (const float*)d_in[10];
  const float* gamma = (const float*)d_in[11];
  const float* fnw = (const float*)d_in[12];
  const float* fnb = (const float*)d_in[13];
  const float* fpw = (const float*)d_in[14];
  const float* fpb = (const float*)d_in[15];
  const float* fpg = (const float*)d_in[16];

  char* ws = (char*)d_ws;
  u8* t = (u8*)(ws);                       //  38,535,168 B (100352x384 fp8)
  u16* U = (u16*)(ws + 38535168);          //  77,070,336 B (100352x384 bf16)
  u8* w1p8 = (u8*)(ws + 115605504);        //     589,824 B
  u8* w2p8 = (u8*)(ws + 116195328);        //     589,824 B
  u8* fpw8 = (u8*)(ws + 116785152);        //     147,456 B
  int* rm1 = (int*)(ws + 116932608);       //     200,704 B
  int* rm2 = (int*)(ws + 117133312);       //     200,704 B
  (void)ws_size; (void)in_sizes; (void)n_in; (void)out_size;

  prep_kernel<<<7168, 256, 0, stream>>>(x, dww, dwb, t, w1, w2, fpw, idx1,
                                        idx2, w1p8, w2p8, fpw8, rm1, rm2);
  mlp_kernel<<<3136, 256, 0, stream>>>(t, rm1, rm2, nw, nb, fnw, fnb, w1p8,
                                       w2p8, fpw8, b1, b2, gamma, fpb, fpg, U);
  unscatter_add_kernel<<<dim3(84, 128), 256, 0, stream>>>(U, x,
                                                          (float*)d_out);
}

// Round 25
// 335.899 us; speedup vs baseline: 1.1673x; 1.1673x over previous
//
#include <hip/hip_runtime.h>
#include <hip/hip_fp8.h>
#include <math.h>

typedef unsigned short u16;
typedef unsigned char u8;
typedef short s16x8 __attribute__((ext_vector_type(8)));
typedef short s16x4 __attribute__((ext_vector_type(4)));
typedef unsigned int u32x4 __attribute__((ext_vector_type(4)));
typedef unsigned int u32x2 __attribute__((ext_vector_type(2)));
typedef float f32x4 __attribute__((ext_vector_type(4)));

__device__ __forceinline__ float bf2f(u16 u) {
  unsigned x = ((unsigned)u) << 16;
  return __builtin_bit_cast(float, x);
}
__device__ __forceinline__ u16 f2bf(float f) {
  unsigned x = __builtin_bit_cast(unsigned, f);
  unsigned r = (x + 0x7FFFu + ((x >> 16) & 1u)) >> 16;
  return (u16)r;
}
__device__ __forceinline__ u8 f2e4_sw(float f) {
  __hip_fp8_e4m3 q(f);
  return (u8)q.__x;
}
// packed f32x2 -> 2 fp8 bytes (hardware v_cvt_pk_fp8_f32 when available)
__device__ __forceinline__ unsigned cvt2e4(float a, float b) {
#if __has_builtin(__builtin_amdgcn_cvt_pk_fp8_f32)
  return (unsigned)__builtin_amdgcn_cvt_pk_fp8_f32(a, b, 0, false) & 0xFFFFu;
#else
  return (unsigned)f2e4_sw(a) | ((unsigned)f2e4_sw(b) << 8);
#endif
}
// branchless e4m3 -> f32 decode: place e|m in f32 fields, scale by 2^120.
// Exact for normals; e4m3 denormals (<2^-6) flush under FTZ (gamma-damped path).
__device__ __forceinline__ float e42f(unsigned b) {
  unsigned x = ((b & 0x80u) << 24) | ((b & 0x7Fu) << 20);
  return __builtin_bit_cast(float, x) * 0x1p120f;
}

// ---- fp8 MFMA: builtin operand type is 'long' (i64) on gfx950 ----
__device__ __forceinline__ f32x4 mfma8(long a, long b, f32x4 c) {
  return __builtin_amdgcn_mfma_f32_16x16x32_fp8_fp8(a, b, c, 0, 0, 0);
}

// ---- in-block gather+LayerNorm (fp8 t): 32 rows -> fp8 octet layout in Alds ----
__device__ __forceinline__ void stage_ln(
    const u8* __restrict__ t, const int* __restrict__ rm, int m_base,
    const float* __restrict__ nw, const float* __restrict__ nb, u8* Alds,
    int tid) {
  int row = tid >> 3, seg = tid & 7;
  const u8* src = t + (size_t)rm[m_base + row] * 384 + seg * 48;
  u32x4 raw[3];
#pragma unroll
  for (int o = 0; o < 3; ++o) raw[o] = *(const u32x4*)(src + o * 16);
  float s = 0.f, q = 0.f;
#pragma unroll
  for (int o = 0; o < 3; ++o)
#pragma unroll
    for (int w = 0; w < 4; ++w) {
      unsigned d = raw[o][w];
      float v0 = e42f(d & 0xFFu);
      float v1 = e42f((d >> 8) & 0xFFu);
      float v2 = e42f((d >> 16) & 0xFFu);
      float v3 = e42f(d >> 24);
      s += (v0 + v1) + (v2 + v3);
      q += (v0 * v0 + v1 * v1) + (v2 * v2 + v3 * v3);
    }
#pragma unroll
  for (int off = 1; off <= 4; off <<= 1) {
    s += __shfl_xor(s, off);
    q += __shfl_xor(q, off);
  }
  float mu = s * (1.f / 384.f);
  float var = q * (1.f / 384.f) - mu * mu;
  float rs = rsqrtf(var + 1e-6f);
#pragma unroll
  for (int o2 = 0; o2 < 6; ++o2) {
    unsigned dA = raw[o2 >> 1][(o2 & 1) * 2];
    unsigned dB = raw[o2 >> 1][(o2 & 1) * 2 + 1];
    int k0 = seg * 48 + o2 * 8;
    float4 w0 = *(const float4*)(nw + k0);
    float4 w1 = *(const float4*)(nw + k0 + 4);
    float4 c0 = *(const float4*)(nb + k0);
    float4 c1 = *(const float4*)(nb + k0 + 4);
    float g0 = (e42f(dA & 0xFFu) - mu) * rs * w0.x + c0.x;
    float g1 = (e42f((dA >> 8) & 0xFFu) - mu) * rs * w0.y + c0.y;
    float g2 = (e42f((dA >> 16) & 0xFFu) - mu) * rs * w0.z + c0.z;
    float g3 = (e42f(dA >> 24) - mu) * rs * w0.w + c0.w;
    float g4 = (e42f(dB & 0xFFu) - mu) * rs * w1.x + c1.x;
    float g5 = (e42f((dB >> 8) & 0xFFu) - mu) * rs * w1.y + c1.y;
    float g6 = (e42f((dB >> 16) & 0xFFu) - mu) * rs * w1.z + c1.z;
    float g7 = (e42f(dB >> 24) - mu) * rs * w1.w + c1.w;
    u32x2 pk;
    pk[0] = cvt2e4(g0, g1) | (cvt2e4(g2, g3) << 16);
    pk[1] = cvt2e4(g4, g5) | (cvt2e4(g6, g7) << 16);
    *(u32x2*)&Alds[((seg * 6 + o2) * 32 + row) * 8] = pk;
  }
}

// ---------------- PREP (merged): dwconv (blocks 0..6143) || pack (6144..7167) ----
__global__ __launch_bounds__(256) void prep_kernel(
    const float* __restrict__ x, const float* __restrict__ dww,
    const float* __restrict__ dwb, u8* __restrict__ t,
    const float* __restrict__ w1, const float* __restrict__ w2,
    const float* __restrict__ fpw, const int* __restrict__ idx1,
    const int* __restrict__ idx2, u8* __restrict__ w1p8, u8* __restrict__ w2p8,
    u8* __restrict__ fpw8, int* __restrict__ rm1, int* __restrict__ rm2) {
  __shared__ __align__(16) u16 plane[8 * 34 * 40];  // 21760 B
  int tid = threadIdx.x;
  int bid = blockIdx.x;
  if (bid >= 6144) {
    const int T1 = 589824, T2 = T1 + 589824, T3 = T2 + 147456,
              T4 = T3 + 50176, T5 = T4 + 50176;
    for (int i = (bid - 6144) * 256 + tid; i < T5; i += 1024 * 256) {
      if (i < T1) {
        int k = i / 1536, n = i - k * 1536;
        w1p8[((size_t)(k >> 3) * 1536 + n) * 8 + (k & 7)] =
            (u8)cvt2e4(w1[i] * 64.f, 0.f);
      } else if (i < T2) {
        int v = i - T1;
        int k = v / 384, n = v - k * 384;
        w2p8[((size_t)(k >> 3) * 384 + n) * 8 + (k & 7)] =
            (u8)cvt2e4(w2[v] * 64.f, 0.f);
      } else if (i < T3) {
        int v = i - T2;
        int k = v / 384, n = v - k * 384;
        fpw8[((size_t)(k >> 3) * 384 + n) * 8 + (k & 7)] =
            (u8)cvt2e4(fpw[v] * 64.f, 0.f);
      } else if (i < T4) {
        int g = i - T3;
        rm1[g] = (g / 392) * 784 + idx1[g];
      } else {
        int g = i - T4;
        rm2[g] = (g / 392) * 784 + idx2[g];
      }
    }
    return;
  }
  // ---- dwconv path ----
  int b = bid / 48, c0 = (bid - b * 48) * 8;
  int ch = tid & 7, row = tid >> 3;
  int c = c0 + ch;

  float wg[49];
#pragma unroll
  for (int k2 = 0; k2 < 49; ++k2) wg[k2] = dww[c * 49 + k2];
  float bias = dwb[c];

  for (int q = tid; q < 1360; q += 256) {
    s16x8 z = {0, 0, 0, 0, 0, 0, 0, 0};
    *(s16x8*)(&plane[q * 8]) = z;
  }
  __syncthreads();
  for (int q = tid; q < 1568; q += 256) {
    int cc = q / 196, seg = q - cc * 196;
    int i = seg / 7, j4 = seg - i * 7;
    const float4 v = *(const float4*)(x + ((size_t)(b * 384 + c0 + cc)) * 784 +
                                      i * 28 + j4 * 4);
    s16x4 p;
    p[0] = (short)f2bf(v.x);
    p[1] = (short)f2bf(v.y);
    p[2] = (short)f2bf(v.z);
    p[3] = (short)f2bf(v.w);
    *(s16x4*)(&plane[cc * 1360 + (3 + i) * 40 + 4 + j4 * 4]) = p;
  }
  __syncthreads();

  if (row < 28) {
    size_t obase = ((size_t)(b * 784 + row * 28)) * 384 + c;
#pragma unroll
    for (int ck = 0; ck < 4; ++ck) {
      float acc[8];
#pragma unroll
      for (int o = 0; o < 8; ++o) acc[o] = bias;
#pragma unroll
      for (int di = 0; di < 7; ++di) {
        const u16* base2 = &plane[ch * 1360 + (row + di) * 40 + ck * 8];
        u32x4 ga = *(const u32x4*)(base2);
        u32x4 gb = *(const u32x4*)(base2 + 8);
        unsigned dw[8] = {ga[0], ga[1], ga[2], ga[3],
                          gb[0], gb[1], gb[2], gb[3]};
        float v[16];
#pragma unroll
        for (int tt = 0; tt < 16; ++tt) {
          unsigned d = dw[tt >> 1];
          v[tt] = (tt & 1) ? __builtin_bit_cast(float, d & 0xFFFF0000u)
                           : __builtin_bit_cast(float, d << 16);
        }
#pragma unroll
        for (int o = 0; o < 8; ++o)
#pragma unroll
          for (int dj = 0; dj < 7; ++dj)
            acc[o] += v[o + dj + 1] * wg[di * 7 + dj];
      }
      // hardware-packed fp8 encode (1 instr / 2 values), byte scatter
      unsigned pkq[4];
#pragma unroll
      for (int p2 = 0; p2 < 4; ++p2)
        pkq[p2] = cvt2e4(acc[2 * p2], acc[2 * p2 + 1]);
      int lim = (ck == 3) ? 4 : 8;
#pragma unroll
      for (int o = 0; o < 8; ++o)
        if (o < lim)
          t[obase + (size_t)(ck * 8 + o) * 384] =
              (u8)(pkq[o >> 1] >> ((o & 1) * 8));
    }
  }
}

// ---------------- MLP (merged): fused MLP (blocks 0..1567) || gemm5 (1568..3135)
__global__ __launch_bounds__(256, 4) void mlp_kernel(
    const u8* __restrict__ t, const int* __restrict__ rm1,
    const int* __restrict__ rm2, const float* __restrict__ nw,
    const float* __restrict__ nb, const float* __restrict__ fnw,
    const float* __restrict__ fnb, const u8* __restrict__ w1p8,
    const u8* __restrict__ w2p8, const u8* __restrict__ fpw8,
    const float* __restrict__ b1, const float* __restrict__ b2,
    const float* __restrict__ gamma, const float* __restrict__ fpb,
    const float* __restrict__ fpg, u16* __restrict__ U) {
  __shared__ __align__(16) u8 Alds[48 * 32 * 8];     // 12288 B
  __shared__ __align__(16) u8 Plds[2][24 * 32 * 8];  // 2 x 6144 B
  int tid = threadIdx.x;
  int wid = tid >> 6, lane = tid & 63;
  int kgl = lane >> 4, rl = lane & 15;
  int cl = lane & 15, rg = (lane >> 4) * 4;
  int bid = blockIdx.x;
  const f32x4 vzero = {0.f, 0.f, 0.f, 0.f};

  if (bid >= 1568) {
    // ---- gemm5 path: U[rm2] = (LN(t[rm2]) @ fp_w + fp_b) * fp_gamma ----
    int m_base = (bid - 1568) * 32;
    stage_ln(t, rm2, m_base, fnw, fnb, Alds, tid);
    f32x4 acc[2][6];
#pragma unroll
    for (int i = 0; i < 2; ++i)
#pragma unroll
      for (int j = 0; j < 6; ++j) acc[i][j] = vzero;
    __syncthreads();
#pragma unroll
    for (int ks = 0; ks < 12; ++ks) {
      long af[2], bw[6];
#pragma unroll
      for (int i = 0; i < 2; ++i)
        af[i] = *(const long*)&Alds[((ks * 4 + kgl) * 32 + i * 16 + rl) * 8];
#pragma unroll
      for (int j = 0; j < 6; ++j) {
        int col = wid * 96 + j * 16 + rl;
        bw[j] = *(const long*)(fpw8 + ((size_t)(ks * 4 + kgl) * 384 + col) * 8);
      }
      __builtin_amdgcn_s_setprio(1);
#pragma unroll
      for (int i = 0; i < 2; ++i)
#pragma unroll
        for (int j = 0; j < 6; ++j)
          acc[i][j] = mfma8(af[i], bw[j], acc[i][j]);
      __builtin_amdgcn_s_setprio(0);
    }
#pragma unroll
    for (int i = 0; i < 2; ++i) {
#pragma unroll
      for (int reg = 0; reg < 4; ++reg) {
        int m = m_base + i * 16 + rg + reg;
        size_t rowoff = (size_t)rm2[m] * 384;
#pragma unroll
        for (int j = 0; j < 6; ++j) {
          int col = wid * 96 + j * 16 + cl;
          float v = (acc[i][j][reg] * 0.015625f + fpb[col]) * fpg[col];
          U[rowoff + col] = f2bf(v);
        }
      }
    }
    return;
  }

  // ---- fused MLP path: U[rm1] = (gelu(LN(t[rm1])@W1+b1)@W2 + b2)*gamma ----
  int m_base = bid * 32;
  stage_ln(t, rm1, m_base, nw, nb, Alds, tid);

  f32x4 accB[2][6];
#pragma unroll
  for (int i = 0; i < 2; ++i)
#pragma unroll
    for (int j = 0; j < 6; ++j) accB[i][j] = vzero;

  __syncthreads();

#pragma unroll 1
  for (int c = 0; c < 8; ++c) {
    u8* Pl = Plds[c & 1];
    f32x4 accA[2][3];
#pragma unroll
    for (int i = 0; i < 2; ++i)
#pragma unroll
      for (int j = 0; j < 3; ++j) accA[i][j] = vzero;
#pragma unroll
    for (int ks = 0; ks < 12; ++ks) {
      long af[2], bw[3];
#pragma unroll
      for (int i = 0; i < 2; ++i)
        af[i] = *(const long*)&Alds[((ks * 4 + kgl) * 32 + i * 16 + rl) * 8];
#pragma unroll
      for (int j = 0; j < 3; ++j) {
        int col = c * 192 + wid * 48 + j * 16 + rl;
        bw[j] = *(const long*)(w1p8 + ((size_t)(ks * 4 + kgl) * 1536 + col) * 8);
      }
      __builtin_amdgcn_s_setprio(1);
#pragma unroll
      for (int i = 0; i < 2; ++i)
#pragma unroll
        for (int j = 0; j < 3; ++j)
          accA[i][j] = mfma8(af[i], bw[j], accA[i][j]);
      __builtin_amdgcn_s_setprio(0);
    }
    float b1v[3];
#pragma unroll
    for (int j = 0; j < 3; ++j) b1v[j] = b1[c * 192 + wid * 48 + j * 16 + cl];
#pragma unroll
    for (int i = 0; i < 2; ++i)
#pragma unroll
      for (int j = 0; j < 3; ++j) {
        int col = wid * 48 + j * 16 + cl;
        float g2[4];
#pragma unroll
        for (int reg = 0; reg < 4; ++reg) {
          float v = accA[i][j][reg] * 0.015625f + b1v[j];
          g2[reg] = v * fminf(fmaxf(0.4255f * v + 0.5f, 0.f), 1.f);
        }
        unsigned p01 = cvt2e4(g2[0], g2[1]);
        unsigned p23 = cvt2e4(g2[2], g2[3]);
        int base = ((col >> 3) * 32 + i * 16 + rg) * 8 + (col & 7);
        Pl[base] = (u8)p01;
        Pl[base + 8] = (u8)(p01 >> 8);
        Pl[base + 16] = (u8)p23;
        Pl[base + 24] = (u8)(p23 >> 8);
      }
    __syncthreads();
#pragma unroll
    for (int ks = 0; ks < 6; ++ks) {
      long ap[2], bw2[6];
#pragma unroll
      for (int i = 0; i < 2; ++i)
        ap[i] = *(const long*)&Pl[((ks * 4 + kgl) * 32 + i * 16 + rl) * 8];
#pragma unroll
      for (int j = 0; j < 6; ++j) {
        int col = wid * 96 + j * 16 + rl;
        int ko2 = c * 24 + ks * 4 + kgl;
        bw2[j] = *(const long*)(w2p8 + ((size_t)ko2 * 384 + col) * 8);
      }
      __builtin_amdgcn_s_setprio(1);
#pragma unroll
      for (int i = 0; i < 2; ++i)
#pragma unroll
        for (int j = 0; j < 6; ++j)
          accB[i][j] = mfma8(ap[i], bw2[j], accB[i][j]);
      __builtin_amdgcn_s_setprio(0);
    }
  }

#pragma unroll
  for (int i = 0; i < 2; ++i) {
#pragma unroll
    for (int reg = 0; reg < 4; ++reg) {
      int m = m_base + i * 16 + rg + reg;
      size_t rowoff = (size_t)rm1[m] * 384;
#pragma unroll
      for (int j = 0; j < 6; ++j) {
        int col = wid * 96 + j * 16 + cl;
        float v = (accB[i][j][reg] * 0.015625f + b2[col]) * gamma[col];
        U[rowoff + col] = f2bf(v);
      }
    }
  }
}

// ---------------- K6: un-transpose (B,N,C)->(B,C,N) + residual add ----------------
__global__ __launch_bounds__(256) void unscatter_add_kernel(
    const u16* __restrict__ U, const float* __restrict__ x,
    float* __restrict__ out) {
  __shared__ float tile[32][129];
  int b = blockIdx.y;
  int ct = blockIdx.x % 12, nt = blockIdx.x / 12;
  int c0 = ct * 32, n0 = nt * 128;
  int tid = threadIdx.x;
#pragma unroll
  for (int it = 0; it < 4; ++it) {
    int q = tid + it * 256;
    int nl = q >> 3, cg = (q & 7) * 4;
    int n = n0 + nl;
    if (n < 784) {
      s16x4 v = *(const s16x4*)(U + ((size_t)(b * 784 + n)) * 384 + c0 + cg);
      tile[cg + 0][nl] = bf2f((u16)v[0]);
      tile[cg + 1][nl] = bf2f((u16)v[1]);
      tile[cg + 2][nl] = bf2f((u16)v[2]);
      tile[cg + 3][nl] = bf2f((u16)v[3]);
    }
  }
  __syncthreads();
#pragma unroll
  for (int it = 0; it < 4; ++it) {
    int q = tid + it * 256;
    int c = q >> 5, nf = (q & 31) * 4;
    int n = n0 + nf;
    if (n + 3 < 784) {
      size_t o = ((size_t)(b * 384 + c0 + c)) * 784 + n;
      float4 xv = *(const float4*)(x + o);
      float4 r;
      r.x = xv.x + tile[c][nf + 0];
      r.y = xv.y + tile[c][nf + 1];
      r.z = xv.z + tile[c][nf + 2];
      r.w = xv.w + tile[c][nf + 3];
      *(float4*)(out + o) = r;
    }
  }
}

extern "C" void kernel_launch(void* const* d_in, const int* in_sizes, int n_in,
                              void* d_out, int out_size, void* d_ws,
                              size_t ws_size, hipStream_t stream) {
  const float* x = (const float*)d_in[0];
  const int* idx1 = (const int*)d_in[1];
  const int* idx2 = (const int*)d_in[2];
  const float* dww = (const float*)d_in[3];
  const float* dwb = (const float*)d_in[4];
  const float* nw = (const float*)d_in[5];
  const float* nb = (const float*)d_in[6];
  const float* w1 = (const float*)d_in[7];
  const float* b1 = (const float*)d_in[8];
  const float* w2 = (const float*)d_in[9];
  const float* b2 = (const float*)d_in[10];
  const float* gamma = (const float*)d_in[11];
  const float* fnw = (const float*)d_in[12];
  const float* fnb = (const float*)d_in[13];
  const float* fpw = (const float*)d_in[14];
  const float* fpb = (const float*)d_in[15];
  const float* fpg = (const float*)d_in[16];

  char* ws = (char*)d_ws;
  u8* t = (u8*)(ws);                       //  38,535,168 B (100352x384 fp8)
  u16* U = (u16*)(ws + 38535168);          //  77,070,336 B (100352x384 bf16)
  u8* w1p8 = (u8*)(ws + 115605504);        //     589,824 B
  u8* w2p8 = (u8*)(ws + 116195328);        //     589,824 B
  u8* fpw8 = (u8*)(ws + 116785152);        //     147,456 B
  int* rm1 = (int*)(ws + 116932608);       //     200,704 B
  int* rm2 = (int*)(ws + 117133312);       //     200,704 B
  (void)ws_size; (void)in_sizes; (void)n_in; (void)out_size;

  prep_kernel<<<7168, 256, 0, stream>>>(x, dww, dwb, t, w1, w2, fpw, idx1,
                                        idx2, w1p8, w2p8, fpw8, rm1, rm2);
  mlp_kernel<<<3136, 256, 0, stream>>>(t, rm1, rm2, nw, nb, fnw, fnb, w1p8,
                                       w2p8, fpw8, b1, b2, gamma, fpb, fpg, U);
  unscatter_add_kernel<<<dim3(84, 128), 256, 0, stream>>>(U, x,
                                                          (float*)d_out);
}

// Round 26
// 331.609 us; speedup vs baseline: 1.1824x; 1.0129x over previous
//
#include <hip/hip_runtime.h>
#include <hip/hip_fp8.h>
#include <math.h>

typedef unsigned short u16;
typedef unsigned char u8;
typedef short s16x8 __attribute__((ext_vector_type(8)));
typedef short s16x4 __attribute__((ext_vector_type(4)));
typedef unsigned int u32x4 __attribute__((ext_vector_type(4)));
typedef unsigned int u32x2 __attribute__((ext_vector_type(2)));
typedef float f32x4 __attribute__((ext_vector_type(4)));

__device__ __forceinline__ float bf2f(u16 u) {
  unsigned x = ((unsigned)u) << 16;
  return __builtin_bit_cast(float, x);
}
__device__ __forceinline__ u16 f2bf(float f) {
  unsigned x = __builtin_bit_cast(unsigned, f);
  unsigned r = (x + 0x7FFFu + ((x >> 16) & 1u)) >> 16;
  return (u16)r;
}
__device__ __forceinline__ u8 f2e4_sw(float f) {
  __hip_fp8_e4m3 q(f);
  return (u8)q.__x;
}
// packed f32x2 -> 2 fp8 bytes (hardware v_cvt_pk_fp8_f32 when available)
__device__ __forceinline__ unsigned cvt2e4(float a, float b) {
#if __has_builtin(__builtin_amdgcn_cvt_pk_fp8_f32)
  return (unsigned)__builtin_amdgcn_cvt_pk_fp8_f32(a, b, 0, false) & 0xFFFFu;
#else
  return (unsigned)f2e4_sw(a) | ((unsigned)f2e4_sw(b) << 8);
#endif
}
// branchless e4m3 -> f32 decode: place e|m in f32 fields, scale by 2^120.
__device__ __forceinline__ float e42f(unsigned b) {
  unsigned x = ((b & 0x80u) << 24) | ((b & 0x7Fu) << 20);
  return __builtin_bit_cast(float, x) * 0x1p120f;
}

// ---- fp8 MFMA: builtin operand type is 'long' (i64) on gfx950 ----
__device__ __forceinline__ f32x4 mfma8(long a, long b, f32x4 c) {
  return __builtin_amdgcn_mfma_f32_16x16x32_fp8_fp8(a, b, c, 0, 0, 0);
}

// ---- in-block gather+LayerNorm (fp8 t): 32 rows -> fp8 octet layout in Alds ----
__device__ __forceinline__ void stage_ln(
    const u8* __restrict__ t, const int* __restrict__ rm, int m_base,
    const float* __restrict__ nw, const float* __restrict__ nb, u8* Alds,
    int tid) {
  int row = tid >> 3, seg = tid & 7;
  const u8* src = t + (size_t)rm[m_base + row] * 384 + seg * 48;
  u32x4 raw[3];
#pragma unroll
  for (int o = 0; o < 3; ++o) raw[o] = *(const u32x4*)(src + o * 16);
  float s = 0.f, q = 0.f;
#pragma unroll
  for (int o = 0; o < 3; ++o)
#pragma unroll
    for (int w = 0; w < 4; ++w) {
      unsigned d = raw[o][w];
      float v0 = e42f(d & 0xFFu);
      float v1 = e42f((d >> 8) & 0xFFu);
      float v2 = e42f((d >> 16) & 0xFFu);
      float v3 = e42f(d >> 24);
      s += (v0 + v1) + (v2 + v3);
      q += (v0 * v0 + v1 * v1) + (v2 * v2 + v3 * v3);
    }
#pragma unroll
  for (int off = 1; off <= 4; off <<= 1) {
    s += __shfl_xor(s, off);
    q += __shfl_xor(q, off);
  }
  float mu = s * (1.f / 384.f);
  float var = q * (1.f / 384.f) - mu * mu;
  float rs = rsqrtf(var + 1e-6f);
#pragma unroll
  for (int o2 = 0; o2 < 6; ++o2) {
    unsigned dA = raw[o2 >> 1][(o2 & 1) * 2];
    unsigned dB = raw[o2 >> 1][(o2 & 1) * 2 + 1];
    int k0 = seg * 48 + o2 * 8;
    float4 w0 = *(const float4*)(nw + k0);
    float4 w1 = *(const float4*)(nw + k0 + 4);
    float4 c0 = *(const float4*)(nb + k0);
    float4 c1 = *(const float4*)(nb + k0 + 4);
    float g0 = (e42f(dA & 0xFFu) - mu) * rs * w0.x + c0.x;
    float g1 = (e42f((dA >> 8) & 0xFFu) - mu) * rs * w0.y + c0.y;
    float g2 = (e42f((dA >> 16) & 0xFFu) - mu) * rs * w0.z + c0.z;
    float g3 = (e42f(dA >> 24) - mu) * rs * w0.w + c0.w;
    float g4 = (e42f(dB & 0xFFu) - mu) * rs * w1.x + c1.x;
    float g5 = (e42f((dB >> 8) & 0xFFu) - mu) * rs * w1.y + c1.y;
    float g6 = (e42f((dB >> 16) & 0xFFu) - mu) * rs * w1.z + c1.z;
    float g7 = (e42f(dB >> 24) - mu) * rs * w1.w + c1.w;
    u32x2 pk;
    pk[0] = cvt2e4(g0, g1) | (cvt2e4(g2, g3) << 16);
    pk[1] = cvt2e4(g4, g5) | (cvt2e4(g6, g7) << 16);
    *(u32x2*)&Alds[((seg * 6 + o2) * 32 + row) * 8] = pk;
  }
}

// ---------------- PREP (merged): dwconv (blocks 0..6143) || pack (6144..7167) ----
__global__ __launch_bounds__(256) void prep_kernel(
    const float* __restrict__ x, const float* __restrict__ dww,
    const float* __restrict__ dwb, u8* __restrict__ t,
    const float* __restrict__ w1, const float* __restrict__ w2,
    const float* __restrict__ fpw, const int* __restrict__ idx1,
    const int* __restrict__ idx2, u8* __restrict__ w1p8, u8* __restrict__ w2p8,
    u8* __restrict__ fpw8, int* __restrict__ rm1, int* __restrict__ rm2) {
  __shared__ __align__(16) u16 plane[8 * 34 * 40];  // 21760 B
  int tid = threadIdx.x;
  int bid = blockIdx.x;
  if (bid >= 6144) {
    const int T1 = 589824, T2 = T1 + 589824, T3 = T2 + 147456,
              T4 = T3 + 50176, T5 = T4 + 50176;
    for (int i = (bid - 6144) * 256 + tid; i < T5; i += 1024 * 256) {
      if (i < T1) {
        int k = i / 1536, n = i - k * 1536;
        w1p8[((size_t)(k >> 3) * 1536 + n) * 8 + (k & 7)] =
            (u8)cvt2e4(w1[i] * 64.f, 0.f);
      } else if (i < T2) {
        int v = i - T1;
        int k = v / 384, n = v - k * 384;
        w2p8[((size_t)(k >> 3) * 384 + n) * 8 + (k & 7)] =
            (u8)cvt2e4(w2[v] * 64.f, 0.f);
      } else if (i < T3) {
        int v = i - T2;
        int k = v / 384, n = v - k * 384;
        fpw8[((size_t)(k >> 3) * 384 + n) * 8 + (k & 7)] =
            (u8)cvt2e4(fpw[v] * 64.f, 0.f);
      } else if (i < T4) {
        int g = i - T3;
        rm1[g] = (g / 392) * 784 + idx1[g];
      } else {
        int g = i - T4;
        rm2[g] = (g / 392) * 784 + idx2[g];
      }
    }
    return;
  }
  // ---- dwconv path ----
  int b = bid / 48, c0 = (bid - b * 48) * 8;
  int ch = tid & 7, row = tid >> 3;
  int c = c0 + ch;

  float wg[49];
#pragma unroll
  for (int k2 = 0; k2 < 49; ++k2) wg[k2] = dww[c * 49 + k2];
  float bias = dwb[c];

  for (int q = tid; q < 1360; q += 256) {
    s16x8 z = {0, 0, 0, 0, 0, 0, 0, 0};
    *(s16x8*)(&plane[q * 8]) = z;
  }
  __syncthreads();
  for (int q = tid; q < 1568; q += 256) {
    int cc = q / 196, seg = q - cc * 196;
    int i = seg / 7, j4 = seg - i * 7;
    const float4 v = *(const float4*)(x + ((size_t)(b * 384 + c0 + cc)) * 784 +
                                      i * 28 + j4 * 4);
    s16x4 p;
    p[0] = (short)f2bf(v.x);
    p[1] = (short)f2bf(v.y);
    p[2] = (short)f2bf(v.z);
    p[3] = (short)f2bf(v.w);
    *(s16x4*)(&plane[cc * 1360 + (3 + i) * 40 + 4 + j4 * 4]) = p;
  }
  __syncthreads();

  if (row < 28) {
    size_t obase = ((size_t)(b * 784 + row * 28)) * 384 + c;
#pragma unroll
    for (int ck = 0; ck < 4; ++ck) {
      float acc[8];
#pragma unroll
      for (int o = 0; o < 8; ++o) acc[o] = bias;
#pragma unroll
      for (int di = 0; di < 7; ++di) {
        const u16* base2 = &plane[ch * 1360 + (row + di) * 40 + ck * 8];
        u32x4 ga = *(const u32x4*)(base2);
        u32x4 gb = *(const u32x4*)(base2 + 8);
        unsigned dw[8] = {ga[0], ga[1], ga[2], ga[3],
                          gb[0], gb[1], gb[2], gb[3]};
        float v[16];
#pragma unroll
        for (int tt = 0; tt < 16; ++tt) {
          unsigned d = dw[tt >> 1];
          v[tt] = (tt & 1) ? __builtin_bit_cast(float, d & 0xFFFF0000u)
                           : __builtin_bit_cast(float, d << 16);
        }
#pragma unroll
        for (int o = 0; o < 8; ++o)
#pragma unroll
          for (int dj = 0; dj < 7; ++dj)
            acc[o] += v[o + dj + 1] * wg[di * 7 + dj];
      }
      // hardware-packed fp8 encode (1 instr / 2 values), byte scatter
      unsigned pkq[4];
#pragma unroll
      for (int p2 = 0; p2 < 4; ++p2)
        pkq[p2] = cvt2e4(acc[2 * p2], acc[2 * p2 + 1]);
      int lim = (ck == 3) ? 4 : 8;
#pragma unroll
      for (int o = 0; o < 8; ++o)
        if (o < lim)
          t[obase + (size_t)(ck * 8 + o) * 384] =
              (u8)(pkq[o >> 1] >> ((o & 1) * 8));
    }
  }
}

// ---------------- MLP (merged): fused MLP (blocks 0..1567) || gemm5 (1568..3135)
__global__ __launch_bounds__(256, 4) void mlp_kernel(
    const u8* __restrict__ t, const int* __restrict__ rm1,
    const int* __restrict__ rm2, const float* __restrict__ nw,
    const float* __restrict__ nb, const float* __restrict__ fnw,
    const float* __restrict__ fnb, const u8* __restrict__ w1p8,
    const u8* __restrict__ w2p8, const u8* __restrict__ fpw8,
    const float* __restrict__ b1, const float* __restrict__ b2,
    const float* __restrict__ gamma, const float* __restrict__ fpb,
    const float* __restrict__ fpg, u16* __restrict__ U) {
  __shared__ __align__(16) u8 Alds[48 * 32 * 8];     // 12288 B
  __shared__ __align__(16) u8 Plds[2][24 * 32 * 8];  // 2 x 6144 B
  int tid = threadIdx.x;
  int wid = tid >> 6, lane = tid & 63;
  int kgl = lane >> 4, rl = lane & 15;
  int cl = lane & 15, rg = (lane >> 4) * 4;
  int bid = blockIdx.x;
  const f32x4 vzero = {0.f, 0.f, 0.f, 0.f};

  if (bid >= 1568) {
    // ---- gemm5 path: U[rm2] = (LN(t[rm2]) @ fp_w + fp_b) * fp_gamma ----
    int m_base = (bid - 1568) * 32;
    stage_ln(t, rm2, m_base, fnw, fnb, Alds, tid);
    f32x4 acc[2][6];
#pragma unroll
    for (int i = 0; i < 2; ++i)
#pragma unroll
      for (int j = 0; j < 6; ++j) acc[i][j] = vzero;
    __syncthreads();
#pragma unroll
    for (int ks = 0; ks < 12; ++ks) {
      long af[2], bw[6];
#pragma unroll
      for (int i = 0; i < 2; ++i)
        af[i] = *(const long*)&Alds[((ks * 4 + kgl) * 32 + i * 16 + rl) * 8];
#pragma unroll
      for (int j = 0; j < 6; ++j) {
        int col = wid * 96 + j * 16 + rl;
        bw[j] = *(const long*)(fpw8 + ((size_t)(ks * 4 + kgl) * 384 + col) * 8);
      }
      __builtin_amdgcn_s_setprio(1);
#pragma unroll
      for (int i = 0; i < 2; ++i)
#pragma unroll
        for (int j = 0; j < 6; ++j)
          acc[i][j] = mfma8(af[i], bw[j], acc[i][j]);
      __builtin_amdgcn_s_setprio(0);
    }
#pragma unroll
    for (int i = 0; i < 2; ++i) {
#pragma unroll
      for (int reg = 0; reg < 4; ++reg) {
        int m = m_base + i * 16 + rg + reg;
        size_t rowoff = (size_t)rm2[m] * 384;
#pragma unroll
        for (int j = 0; j < 6; ++j) {
          int col = wid * 96 + j * 16 + cl;
          float v = (acc[i][j][reg] * 0.015625f + fpb[col]) * fpg[col];
          U[rowoff + col] = f2bf(v);
        }
      }
    }
    return;
  }

  // ---- fused MLP path: U[rm1] = (gelu(LN(t[rm1])@W1+b1)@W2 + b2)*gamma ----
  int m_base = bid * 32;
  stage_ln(t, rm1, m_base, nw, nb, Alds, tid);

  f32x4 accB[2][6];
#pragma unroll
  for (int i = 0; i < 2; ++i)
#pragma unroll
    for (int j = 0; j < 6; ++j) accB[i][j] = vzero;

  __syncthreads();

#pragma unroll 1
  for (int c = 0; c < 8; ++c) {
    u8* Pl = Plds[c & 1];
    f32x4 accA[2][3];
#pragma unroll
    for (int i = 0; i < 2; ++i)
#pragma unroll
      for (int j = 0; j < 3; ++j) accA[i][j] = vzero;
#pragma unroll
    for (int ks = 0; ks < 12; ++ks) {
      long af[2], bw[3];
#pragma unroll
      for (int i = 0; i < 2; ++i)
        af[i] = *(const long*)&Alds[((ks * 4 + kgl) * 32 + i * 16 + rl) * 8];
#pragma unroll
      for (int j = 0; j < 3; ++j) {
        int col = c * 192 + wid * 48 + j * 16 + rl;
        bw[j] = *(const long*)(w1p8 + ((size_t)(ks * 4 + kgl) * 1536 + col) * 8);
      }
      __builtin_amdgcn_s_setprio(1);
#pragma unroll
      for (int i = 0; i < 2; ++i)
#pragma unroll
        for (int j = 0; j < 3; ++j)
          accA[i][j] = mfma8(af[i], bw[j], accA[i][j]);
      __builtin_amdgcn_s_setprio(0);
    }
    float b1v[3];
#pragma unroll
    for (int j = 0; j < 3; ++j) b1v[j] = b1[c * 192 + wid * 48 + j * 16 + cl];
#pragma unroll
    for (int i = 0; i < 2; ++i)
#pragma unroll
      for (int j = 0; j < 3; ++j) {
        int col = wid * 48 + j * 16 + cl;
        float g2[4];
#pragma unroll
        for (int reg = 0; reg < 4; ++reg) {
          float v = accA[i][j][reg] * 0.015625f + b1v[j];
          g2[reg] = v * fminf(fmaxf(0.4255f * v + 0.5f, 0.f), 1.f);
        }
        unsigned p01 = cvt2e4(g2[0], g2[1]);
        unsigned p23 = cvt2e4(g2[2], g2[3]);
        int base = ((col >> 3) * 32 + i * 16 + rg) * 8 + (col & 7);
        Pl[base] = (u8)p01;
        Pl[base + 8] = (u8)(p01 >> 8);
        Pl[base + 16] = (u8)p23;
        Pl[base + 24] = (u8)(p23 >> 8);
      }
    __syncthreads();
#pragma unroll
    for (int ks = 0; ks < 6; ++ks) {
      long ap[2], bw2[6];
#pragma unroll
      for (int i = 0; i < 2; ++i)
        ap[i] = *(const long*)&Pl[((ks * 4 + kgl) * 32 + i * 16 + rl) * 8];
#pragma unroll
      for (int j = 0; j < 6; ++j) {
        int col = wid * 96 + j * 16 + rl;
        int ko2 = c * 24 + ks * 4 + kgl;
        bw2[j] = *(const long*)(w2p8 + ((size_t)ko2 * 384 + col) * 8);
      }
      __builtin_amdgcn_s_setprio(1);
#pragma unroll
      for (int i = 0; i < 2; ++i)
#pragma unroll
        for (int j = 0; j < 6; ++j)
          accB[i][j] = mfma8(ap[i], bw2[j], accB[i][j]);
      __builtin_amdgcn_s_setprio(0);
    }
  }

#pragma unroll
  for (int i = 0; i < 2; ++i) {
#pragma unroll
    for (int reg = 0; reg < 4; ++reg) {
      int m = m_base + i * 16 + rg + reg;
      size_t rowoff = (size_t)rm1[m] * 384;
#pragma unroll
      for (int j = 0; j < 6; ++j) {
        int col = wid * 96 + j * 16 + cl;
        float v = (accB[i][j][reg] * 0.015625f + b2[col]) * gamma[col];
        U[rowoff + col] = f2bf(v);
      }
    }
  }
}

// ---------------- K6: un-transpose (B,N,C)->(B,C,N) + residual add ----------------
// 64c x 64n tile: U-reads are 128B-contiguous runs (16 lanes x 8B), write/x
// float4 256B runs. LDS 16.6 KB. Grid (6*13, 128); n bounds-guarded.
__global__ __launch_bounds__(256) void unscatter_add_kernel(
    const u16* __restrict__ U, const float* __restrict__ x,
    float* __restrict__ out) {
  __shared__ float tile[64][65];
  int b = blockIdx.y;
  int ct = blockIdx.x % 6, nt = blockIdx.x / 6;
  int c0 = ct * 64, n0 = nt * 64;
  int tid = threadIdx.x;
#pragma unroll
  for (int it = 0; it < 4; ++it) {
    int q = tid + it * 256;      // 1024 = 64n x 16 c-quads
    int nl = q >> 4, cg = (q & 15) * 4;
    int n = n0 + nl;
    if (n < 784) {
      s16x4 v = *(const s16x4*)(U + ((size_t)(b * 784 + n)) * 384 + c0 + cg);
      tile[cg + 0][nl] = bf2f((u16)v[0]);
      tile[cg + 1][nl] = bf2f((u16)v[1]);
      tile[cg + 2][nl] = bf2f((u16)v[2]);
      tile[cg + 3][nl] = bf2f((u16)v[3]);
    }
  }
  __syncthreads();
#pragma unroll
  for (int it = 0; it < 4; ++it) {
    int q = tid + it * 256;      // 1024 = 64c x 16 n-quads
    int c = q >> 4, nf = (q & 15) * 4;
    int n = n0 + nf;
    if (n + 3 < 784) {
      size_t o = ((size_t)(b * 384 + c0 + c)) * 784 + n;
      float4 xv = *(const float4*)(x + o);
      float4 r;
      r.x = xv.x + tile[c][nf + 0];
      r.y = xv.y + tile[c][nf + 1];
      r.z = xv.z + tile[c][nf + 2];
      r.w = xv.w + tile[c][nf + 3];
      *(float4*)(out + o) = r;
    }
  }
}

extern "C" void kernel_launch(void* const* d_in, const int* in_sizes, int n_in,
                              void* d_out, int out_size, void* d_ws,
                              size_t ws_size, hipStream_t stream) {
  const float* x = (const float*)d_in[0];
  const int* idx1 = (const int*)d_in[1];
  const int* idx2 = (const int*)d_in[2];
  const float* dww = (const float*)d_in[3];
  const float* dwb = (const float*)d_in[4];
  const float* nw = (const float*)d_in[5];
  const float* nb = (const float*)d_in[6];
  const float* w1 = (const float*)d_in[7];
  const float* b1 = (const float*)d_in[8];
  const float* w2 = (const float*)d_in[9];
  const float* b2 = (const float*)d_in[10];
  const float* gamma = (const float*)d_in[11];
  const float* fnw = (const float*)d_in[12];
  const float* fnb = (const float*)d_in[13];
  const float* fpw = (const float*)d_in[14];
  const float* fpb = (const float*)d_in[15];
  const float* fpg = (const float*)d_in[16];

  char* ws = (char*)d_ws;
  u8* t = (u8*)(ws);                       //  38,535,168 B (100352x384 fp8)
  u16* U = (u16*)(ws + 38535168);          //  77,070,336 B (100352x384 bf16)
  u8* w1p8 = (u8*)(ws + 115605504);        //     589,824 B
  u8* w2p8 = (u8*)(ws + 116195328);        //     589,824 B
  u8* fpw8 = (u8*)(ws + 116785152);        //     147,456 B
  int* rm1 = (int*)(ws + 116932608);       //     200,704 B
  int* rm2 = (int*)(ws + 117133312);       //     200,704 B
  (void)ws_size; (void)in_sizes; (void)n_in; (void)out_size;

  prep_kernel<<<7168, 256, 0, stream>>>(x, dww, dwb, t, w1, w2, fpw, idx1,
                                        idx2, w1p8, w2p8, fpw8, rm1, rm2);
  mlp_kernel<<<3136, 256, 0, stream>>>(t, rm1, rm2, nw, nb, fnw, fnb, w1p8,
                                       w2p8, fpw8, b1, b2, gamma, fpb, fpg, U);
  unscatter_add_kernel<<<dim3(78, 128), 256, 0, stream>>>(U, x,
                                                          (float*)d_out);
}

// Round 27
// 319.610 us; speedup vs baseline: 1.2268x; 1.0375x over previous
//
#include <hip/hip_runtime.h>
#include <hip/hip_fp8.h>
#include <math.h>

typedef unsigned short u16;
typedef unsigned char u8;
typedef short s16x8 __attribute__((ext_vector_type(8)));
typedef short s16x4 __attribute__((ext_vector_type(4)));
typedef unsigned int u32x4 __attribute__((ext_vector_type(4)));
typedef unsigned int u32x2 __attribute__((ext_vector_type(2)));
typedef float f32x4 __attribute__((ext_vector_type(4)));

__device__ __forceinline__ float bf2f(u16 u) {
  unsigned x = ((unsigned)u) << 16;
  return __builtin_bit_cast(float, x);
}
__device__ __forceinline__ u16 f2bf(float f) {
  unsigned x = __builtin_bit_cast(unsigned, f);
  unsigned r = (x + 0x7FFFu + ((x >> 16) & 1u)) >> 16;
  return (u16)r;
}
__device__ __forceinline__ u8 f2e4_sw(float f) {
  __hip_fp8_e4m3 q(f);
  return (u8)q.__x;
}
// packed f32x2 -> 2 fp8 bytes (hardware v_cvt_pk_fp8_f32 when available)
__device__ __forceinline__ unsigned cvt2e4(float a, float b) {
#if __has_builtin(__builtin_amdgcn_cvt_pk_fp8_f32)
  return (unsigned)__builtin_amdgcn_cvt_pk_fp8_f32(a, b, 0, false) & 0xFFFFu;
#else
  return (unsigned)f2e4_sw(a) | ((unsigned)f2e4_sw(b) << 8);
#endif
}
// branchless e4m3 -> f32 decode: place e|m in f32 fields, scale by 2^120.
__device__ __forceinline__ float e42f(unsigned b) {
  unsigned x = ((b & 0x80u) << 24) | ((b & 0x7Fu) << 20);
  return __builtin_bit_cast(float, x) * 0x1p120f;
}

// ---- fp8 MFMA: builtin operand type is 'long' (i64) on gfx950 ----
__device__ __forceinline__ f32x4 mfma8(long a, long b, f32x4 c) {
  return __builtin_amdgcn_mfma_f32_16x16x32_fp8_fp8(a, b, c, 0, 0, 0);
}

// ---- in-block gather+LayerNorm (fp8 t): 32 rows -> fp8 octet layout in Alds ----
__device__ __forceinline__ void stage_ln(
    const u8* __restrict__ t, const int* __restrict__ rm, int m_base,
    const float* __restrict__ nw, const float* __restrict__ nb, u8* Alds,
    int tid) {
  int row = tid >> 3, seg = tid & 7;
  const u8* src = t + (size_t)rm[m_base + row] * 384 + seg * 48;
  u32x4 raw[3];
#pragma unroll
  for (int o = 0; o < 3; ++o) raw[o] = *(const u32x4*)(src + o * 16);
  float s = 0.f, q = 0.f;
#pragma unroll
  for (int o = 0; o < 3; ++o)
#pragma unroll
    for (int w = 0; w < 4; ++w) {
      unsigned d = raw[o][w];
      float v0 = e42f(d & 0xFFu);
      float v1 = e42f((d >> 8) & 0xFFu);
      float v2 = e42f((d >> 16) & 0xFFu);
      float v3 = e42f(d >> 24);
      s += (v0 + v1) + (v2 + v3);
      q += (v0 * v0 + v1 * v1) + (v2 * v2 + v3 * v3);
    }
#pragma unroll
  for (int off = 1; off <= 4; off <<= 1) {
    s += __shfl_xor(s, off);
    q += __shfl_xor(q, off);
  }
  float mu = s * (1.f / 384.f);
  float var = q * (1.f / 384.f) - mu * mu;
  float rs = rsqrtf(var + 1e-6f);
#pragma unroll
  for (int o2 = 0; o2 < 6; ++o2) {
    unsigned dA = raw[o2 >> 1][(o2 & 1) * 2];
    unsigned dB = raw[o2 >> 1][(o2 & 1) * 2 + 1];
    int k0 = seg * 48 + o2 * 8;
    float4 w0 = *(const float4*)(nw + k0);
    float4 w1 = *(const float4*)(nw + k0 + 4);
    float4 c0 = *(const float4*)(nb + k0);
    float4 c1 = *(const float4*)(nb + k0 + 4);
    float g0 = (e42f(dA & 0xFFu) - mu) * rs * w0.x + c0.x;
    float g1 = (e42f((dA >> 8) & 0xFFu) - mu) * rs * w0.y + c0.y;
    float g2 = (e42f((dA >> 16) & 0xFFu) - mu) * rs * w0.z + c0.z;
    float g3 = (e42f(dA >> 24) - mu) * rs * w0.w + c0.w;
    float g4 = (e42f(dB & 0xFFu) - mu) * rs * w1.x + c1.x;
    float g5 = (e42f((dB >> 8) & 0xFFu) - mu) * rs * w1.y + c1.y;
    float g6 = (e42f((dB >> 16) & 0xFFu) - mu) * rs * w1.z + c1.z;
    float g7 = (e42f(dB >> 24) - mu) * rs * w1.w + c1.w;
    u32x2 pk;
    pk[0] = cvt2e4(g0, g1) | (cvt2e4(g2, g3) << 16);
    pk[1] = cvt2e4(g4, g5) | (cvt2e4(g6, g7) << 16);
    *(u32x2*)&Alds[((seg * 6 + o2) * 32 + row) * 8] = pk;
  }
}

// ---------------- PREP (merged): dwconv (blocks 0..6143) || pack (6144..7167) ----
__global__ __launch_bounds__(256) void prep_kernel(
    const float* __restrict__ x, const float* __restrict__ dww,
    const float* __restrict__ dwb, u8* __restrict__ t,
    const float* __restrict__ w1, const float* __restrict__ w2,
    const float* __restrict__ fpw, const int* __restrict__ idx1,
    const int* __restrict__ idx2, u8* __restrict__ w1p8, u8* __restrict__ w2p8,
    u8* __restrict__ fpw8, int* __restrict__ rm1, int* __restrict__ rm2,
    u8* __restrict__ sel) {
  __shared__ __align__(16) u16 plane[8 * 34 * 40];  // 21760 B
  int tid = threadIdx.x;
  int bid = blockIdx.x;
  if (bid >= 6144) {
    const int T1 = 589824, T2 = T1 + 589824, T3 = T2 + 147456,
              T4 = T3 + 50176, T5 = T4 + 50176;
    for (int i = (bid - 6144) * 256 + tid; i < T5; i += 1024 * 256) {
      if (i < T1) {
        int k = i / 1536, n = i - k * 1536;
        w1p8[((size_t)(k >> 3) * 1536 + n) * 8 + (k & 7)] =
            (u8)cvt2e4(w1[i] * 64.f, 0.f);
      } else if (i < T2) {
        int v = i - T1;
        int k = v / 384, n = v - k * 384;
        w2p8[((size_t)(k >> 3) * 384 + n) * 8 + (k & 7)] =
            (u8)cvt2e4(w2[v] * 64.f, 0.f);
      } else if (i < T3) {
        int v = i - T2;
        int k = v / 384, n = v - k * 384;
        fpw8[((size_t)(k >> 3) * 384 + n) * 8 + (k & 7)] =
            (u8)cvt2e4(fpw[v] * 64.f, 0.f);
      } else if (i < T4) {
        int g = i - T3;
        int r = (g / 392) * 784 + idx1[g];
        rm1[g] = r;
        sel[r] = 0;
      } else {
        int g = i - T4;
        int r = (g / 392) * 784 + idx2[g];
        rm2[g] = r;
        sel[r] = 1;
      }
    }
    return;
  }
  // ---- dwconv path ----
  int b = bid / 48, c0 = (bid - b * 48) * 8;
  int ch = tid & 7, row = tid >> 3;
  int c = c0 + ch;

  float wg[49];
#pragma unroll
  for (int k2 = 0; k2 < 49; ++k2) wg[k2] = dww[c * 49 + k2];
  float bias = dwb[c];

  for (int q = tid; q < 1360; q += 256) {
    s16x8 z = {0, 0, 0, 0, 0, 0, 0, 0};
    *(s16x8*)(&plane[q * 8]) = z;
  }
  __syncthreads();
  for (int q = tid; q < 1568; q += 256) {
    int cc = q / 196, seg = q - cc * 196;
    int i = seg / 7, j4 = seg - i * 7;
    const float4 v = *(const float4*)(x + ((size_t)(b * 384 + c0 + cc)) * 784 +
                                      i * 28 + j4 * 4);
    s16x4 p;
    p[0] = (short)f2bf(v.x);
    p[1] = (short)f2bf(v.y);
    p[2] = (short)f2bf(v.z);
    p[3] = (short)f2bf(v.w);
    *(s16x4*)(&plane[cc * 1360 + (3 + i) * 40 + 4 + j4 * 4]) = p;
  }
  __syncthreads();

  if (row < 28) {
    size_t obase = ((size_t)(b * 784 + row * 28)) * 384 + c;
#pragma unroll
    for (int ck = 0; ck < 4; ++ck) {
      float acc[8];
#pragma unroll
      for (int o = 0; o < 8; ++o) acc[o] = bias;
#pragma unroll
      for (int di = 0; di < 7; ++di) {
        const u16* base2 = &plane[ch * 1360 + (row + di) * 40 + ck * 8];
        u32x4 ga = *(const u32x4*)(base2);
        u32x4 gb = *(const u32x4*)(base2 + 8);
        unsigned dw[8] = {ga[0], ga[1], ga[2], ga[3],
                          gb[0], gb[1], gb[2], gb[3]};
        float v[16];
#pragma unroll
        for (int tt = 0; tt < 16; ++tt) {
          unsigned d = dw[tt >> 1];
          v[tt] = (tt & 1) ? __builtin_bit_cast(float, d & 0xFFFF0000u)
                           : __builtin_bit_cast(float, d << 16);
        }
#pragma unroll
        for (int o = 0; o < 8; ++o)
#pragma unroll
          for (int dj = 0; dj < 7; ++dj)
            acc[o] += v[o + dj + 1] * wg[di * 7 + dj];
      }
      unsigned pkq[4];
#pragma unroll
      for (int p2 = 0; p2 < 4; ++p2)
        pkq[p2] = cvt2e4(acc[2 * p2], acc[2 * p2 + 1]);
      int lim = (ck == 3) ? 4 : 8;
#pragma unroll
      for (int o = 0; o < 8; ++o)
        if (o < lim)
          t[obase + (size_t)(ck * 8 + o) * 384] =
              (u8)(pkq[o >> 1] >> ((o & 1) * 8));
    }
  }
}

// ---------------- MLP (merged): fused MLP (blocks 0..1567) || gemm5 (1568..3135)
// U stored fp8 PRE-gamma (gamma applied in unscatter via sel map).
__global__ __launch_bounds__(256, 4) void mlp_kernel(
    const u8* __restrict__ t, const int* __restrict__ rm1,
    const int* __restrict__ rm2, const float* __restrict__ nw,
    const float* __restrict__ nb, const float* __restrict__ fnw,
    const float* __restrict__ fnb, const u8* __restrict__ w1p8,
    const u8* __restrict__ w2p8, const u8* __restrict__ fpw8,
    const float* __restrict__ b1, const float* __restrict__ b2,
    const float* __restrict__ fpb, u8* __restrict__ U) {
  __shared__ __align__(16) u8 Alds[48 * 32 * 8];     // 12288 B
  __shared__ __align__(16) u8 Plds[2][24 * 32 * 8];  // 2 x 6144 B
  int tid = threadIdx.x;
  int wid = tid >> 6, lane = tid & 63;
  int kgl = lane >> 4, rl = lane & 15;
  int cl = lane & 15, rg = (lane >> 4) * 4;
  int bid = blockIdx.x;
  const f32x4 vzero = {0.f, 0.f, 0.f, 0.f};

  if (bid >= 1568) {
    // ---- gemm5 path: U[rm2] = fp8(LN(t[rm2]) @ fp_w + fp_b) ----
    int m_base = (bid - 1568) * 32;
    stage_ln(t, rm2, m_base, fnw, fnb, Alds, tid);
    f32x4 acc[2][6];
#pragma unroll
    for (int i = 0; i < 2; ++i)
#pragma unroll
      for (int j = 0; j < 6; ++j) acc[i][j] = vzero;
    __syncthreads();
#pragma unroll
    for (int ks = 0; ks < 12; ++ks) {
      long af[2], bw[6];
#pragma unroll
      for (int i = 0; i < 2; ++i)
        af[i] = *(const long*)&Alds[((ks * 4 + kgl) * 32 + i * 16 + rl) * 8];
#pragma unroll
      for (int j = 0; j < 6; ++j) {
        int col = wid * 96 + j * 16 + rl;
        bw[j] = *(const long*)(fpw8 + ((size_t)(ks * 4 + kgl) * 384 + col) * 8);
      }
      __builtin_amdgcn_s_setprio(1);
#pragma unroll
      for (int i = 0; i < 2; ++i)
#pragma unroll
        for (int j = 0; j < 6; ++j)
          acc[i][j] = mfma8(af[i], bw[j], acc[i][j]);
      __builtin_amdgcn_s_setprio(0);
    }
#pragma unroll
    for (int i = 0; i < 2; ++i) {
#pragma unroll
      for (int reg = 0; reg < 4; ++reg) {
        int m = m_base + i * 16 + rg + reg;
        size_t rowoff = (size_t)rm2[m] * 384;
#pragma unroll
        for (int j = 0; j < 6; ++j) {
          int col = wid * 96 + j * 16 + cl;
          float v = acc[i][j][reg] * 0.015625f + fpb[col];
          U[rowoff + col] = (u8)cvt2e4(v, 0.f);
        }
      }
    }
    return;
  }

  // ---- fused MLP path: U[rm1] = fp8(gelu(LN(t[rm1])@W1+b1)@W2 + b2) ----
  int m_base = bid * 32;
  stage_ln(t, rm1, m_base, nw, nb, Alds, tid);

  f32x4 accB[2][6];
#pragma unroll
  for (int i = 0; i < 2; ++i)
#pragma unroll
    for (int j = 0; j < 6; ++j) accB[i][j] = vzero;

  __syncthreads();

#pragma unroll 1
  for (int c = 0; c < 8; ++c) {
    u8* Pl = Plds[c & 1];
    f32x4 accA[2][3];
#pragma unroll
    for (int i = 0; i < 2; ++i)
#pragma unroll
      for (int j = 0; j < 3; ++j) accA[i][j] = vzero;
#pragma unroll
    for (int ks = 0; ks < 12; ++ks) {
      long af[2], bw[3];
#pragma unroll
      for (int i = 0; i < 2; ++i)
        af[i] = *(const long*)&Alds[((ks * 4 + kgl) * 32 + i * 16 + rl) * 8];
#pragma unroll
      for (int j = 0; j < 3; ++j) {
        int col = c * 192 + wid * 48 + j * 16 + rl;
        bw[j] = *(const long*)(w1p8 + ((size_t)(ks * 4 + kgl) * 1536 + col) * 8);
      }
      __builtin_amdgcn_s_setprio(1);
#pragma unroll
      for (int i = 0; i < 2; ++i)
#pragma unroll
        for (int j = 0; j < 3; ++j)
          accA[i][j] = mfma8(af[i], bw[j], accA[i][j]);
      __builtin_amdgcn_s_setprio(0);
    }
    float b1v[3];
#pragma unroll
    for (int j = 0; j < 3; ++j) b1v[j] = b1[c * 192 + wid * 48 + j * 16 + cl];
#pragma unroll
    for (int i = 0; i < 2; ++i)
#pragma unroll
      for (int j = 0; j < 3; ++j) {
        int col = wid * 48 + j * 16 + cl;
        float g2[4];
#pragma unroll
        for (int reg = 0; reg < 4; ++reg) {
          float v = accA[i][j][reg] * 0.015625f + b1v[j];
          g2[reg] = v * fminf(fmaxf(0.4255f * v + 0.5f, 0.f), 1.f);
        }
        unsigned p01 = cvt2e4(g2[0], g2[1]);
        unsigned p23 = cvt2e4(g2[2], g2[3]);
        int base = ((col >> 3) * 32 + i * 16 + rg) * 8 + (col & 7);
        Pl[base] = (u8)p01;
        Pl[base + 8] = (u8)(p01 >> 8);
        Pl[base + 16] = (u8)p23;
        Pl[base + 24] = (u8)(p23 >> 8);
      }
    __syncthreads();
#pragma unroll
    for (int ks = 0; ks < 6; ++ks) {
      long ap[2], bw2[6];
#pragma unroll
      for (int i = 0; i < 2; ++i)
        ap[i] = *(const long*)&Pl[((ks * 4 + kgl) * 32 + i * 16 + rl) * 8];
#pragma unroll
      for (int j = 0; j < 6; ++j) {
        int col = wid * 96 + j * 16 + rl;
        int ko2 = c * 24 + ks * 4 + kgl;
        bw2[j] = *(const long*)(w2p8 + ((size_t)ko2 * 384 + col) * 8);
      }
      __builtin_amdgcn_s_setprio(1);
#pragma unroll
      for (int i = 0; i < 2; ++i)
#pragma unroll
        for (int j = 0; j < 6; ++j)
          accB[i][j] = mfma8(ap[i], bw2[j], accB[i][j]);
      __builtin_amdgcn_s_setprio(0);
    }
  }

#pragma unroll
  for (int i = 0; i < 2; ++i) {
#pragma unroll
    for (int reg = 0; reg < 4; ++reg) {
      int m = m_base + i * 16 + rg + reg;
      size_t rowoff = (size_t)rm1[m] * 384;
#pragma unroll
      for (int j = 0; j < 6; ++j) {
        int col = wid * 96 + j * 16 + cl;
        float v = accB[i][j][reg] * 0.015625f + b2[col];
        U[rowoff + col] = (u8)cvt2e4(v, 0.f);
      }
    }
  }
}

// ---------------- K6: un-transpose (B,N,C)->(B,C,N) + gamma + residual add ----
// 64c x 64n tile; U fp8 reads (16 lanes x 4B = 64B runs); gamma selected per
// token via sel map (rm1->gamma, rm2->fp_gamma); write/x float4 256B runs.
__global__ __launch_bounds__(256) void unscatter_add_kernel(
    const u8* __restrict__ U, const u8* __restrict__ sel,
    const float* __restrict__ gamma, const float* __restrict__ fpg,
    const float* __restrict__ x, float* __restrict__ out) {
  __shared__ float tile[64][65];
  int b = blockIdx.y;
  int ct = blockIdx.x % 6, nt = blockIdx.x / 6;
  int c0 = ct * 64, n0 = nt * 64;
  int tid = threadIdx.x;
#pragma unroll
  for (int it = 0; it < 4; ++it) {
    int q = tid + it * 256;      // 1024 = 64n x 16 c-quads
    int nl = q >> 4, cg = (q & 15) * 4;
    int n = n0 + nl;
    if (n < 784) {
      unsigned v = *(const unsigned*)(U + ((size_t)(b * 784 + n)) * 384 + c0 + cg);
      int s = sel[b * 784 + n];
      float4 ga = *(const float4*)(gamma + c0 + cg);
      float4 gb = *(const float4*)(fpg + c0 + cg);
      float4 gs;
      gs.x = s ? gb.x : ga.x;
      gs.y = s ? gb.y : ga.y;
      gs.z = s ? gb.z : ga.z;
      gs.w = s ? gb.w : ga.w;
      tile[cg + 0][nl] = e42f(v & 0xFFu) * gs.x;
      tile[cg + 1][nl] = e42f((v >> 8) & 0xFFu) * gs.y;
      tile[cg + 2][nl] = e42f((v >> 16) & 0xFFu) * gs.z;
      tile[cg + 3][nl] = e42f(v >> 24) * gs.w;
    }
  }
  __syncthreads();
#pragma unroll
  for (int it = 0; it < 4; ++it) {
    int q = tid + it * 256;      // 1024 = 64c x 16 n-quads
    int c = q >> 4, nf = (q & 15) * 4;
    int n = n0 + nf;
    if (n + 3 < 784) {
      size_t o = ((size_t)(b * 384 + c0 + c)) * 784 + n;
      float4 xv = *(const float4*)(x + o);
      float4 r;
      r.x = xv.x + tile[c][nf + 0];
      r.y = xv.y + tile[c][nf + 1];
      r.z = xv.z + tile[c][nf + 2];
      r.w = xv.w + tile[c][nf + 3];
      *(float4*)(out + o) = r;
    }
  }
}

extern "C" void kernel_launch(void* const* d_in, const int* in_sizes, int n_in,
                              void* d_out, int out_size, void* d_ws,
                              size_t ws_size, hipStream_t stream) {
  const float* x = (const float*)d_in[0];
  const int* idx1 = (const int*)d_in[1];
  const int* idx2 = (const int*)d_in[2];
  const float* dww = (const float*)d_in[3];
  const float* dwb = (const float*)d_in[4];
  const float* nw = (const float*)d_in[5];
  const float* nb = (const float*)d_in[6];
  const float* w1 = (const float*)d_in[7];
  const float* b1 = (const float*)d_in[8];
  const float* w2 = (const float*)d_in[9];
  const float* b2 = (const float*)d_in[10];
  const float* gamma = (const float*)d_in[11];
  const float* fnw = (const float*)d_in[12];
  const float* fnb = (const float*)d_in[13];
  const float* fpw = (const float*)d_in[14];
  const float* fpb = (const float*)d_in[15];
  const float* fpg = (const float*)d_in[16];

  char* ws = (char*)d_ws;
  u8* t = (u8*)(ws);                       //  38,535,168 B (100352x384 fp8)
  u8* U = (u8*)(ws + 38535168);            //  38,535,168 B (100352x384 fp8)
  u8* w1p8 = (u8*)(ws + 77070336);         //     589,824 B
  u8* w2p8 = (u8*)(ws + 77660160);         //     589,824 B
  u8* fpw8 = (u8*)(ws + 78249984);         //     147,456 B
  int* rm1 = (int*)(ws + 78397440);        //     200,704 B
  int* rm2 = (int*)(ws + 78598144);        //     200,704 B
  u8* sel = (u8*)(ws + 78798848);          //     100,352 B
  (void)ws_size; (void)in_sizes; (void)n_in; (void)out_size;

  prep_kernel<<<7168, 256, 0, stream>>>(x, dww, dwb, t, w1, w2, fpw, idx1,
                                        idx2, w1p8, w2p8, fpw8, rm1, rm2, sel);
  mlp_kernel<<<3136, 256, 0, stream>>>(t, rm1, rm2, nw, nb, fnw, fnb, w1p8,
                                       w2p8, fpw8, b1, b2, fpb, U);
  unscatter_add_kernel<<<dim3(78, 128), 256, 0, stream>>>(U, sel, gamma, fpg,
                                                          x, (float*)d_out);
}